// Round 1
// baseline (376.188 us; speedup 1.0000x reference)
//
#include <hip/hip_runtime.h>
#include <stdint.h>

typedef unsigned short u16;
typedef short short8 __attribute__((ext_vector_type(8)));
typedef float f32x4 __attribute__((ext_vector_type(4)));

#define S_LEN 2048
#define NQH 32
#define NKH 8
#define DHD 64

__device__ __forceinline__ float b2f(u16 u){
  union { uint32_t i; float f; } c; c.i = ((uint32_t)u) << 16; return c.f;
}
__device__ __forceinline__ u16 f2b(float f){
  union { float f; uint32_t i; } c; c.f = f;
  uint32_t r = c.i + 0x7fffu + ((c.i >> 16) & 1u);
  return (u16)(r >> 16);
}
__device__ __forceinline__ void gload_lds16(const void* g, void* l){
  __builtin_amdgcn_global_load_lds((const __attribute__((address_space(1))) uint32_t*)g,
                                   (__attribute__((address_space(3))) uint32_t*)l, 16, 0, 0);
}

// ---------------- fp32 -> bf16 convert ----------------
__global__ __launch_bounds__(256) void cvt_f32_bf16(const float* __restrict__ in,
                                                    u16* __restrict__ out, int n4){
  int i = blockIdx.x * 256 + threadIdx.x;
  if (i >= n4) return;
  float4 v = ((const float4*)in)[i];
  uint2 o;
  o.x = (uint32_t)f2b(v.x) | ((uint32_t)f2b(v.y) << 16);
  o.y = (uint32_t)f2b(v.z) | ((uint32_t)f2b(v.w) << 16);
  ((uint2*)out)[i] = o;
}

// ---------------- bf16 GEMM: C[M][N] = A[M][K] * B[N][K]^T ----------------
// 128x128 tile, BK=64, 4 waves (2x2 of 64x64), mfma_f32_16x16x32_bf16.
// LDS tiles [128][64] bf16, XOR-involution swizzle (16B chunk ^ (row&7)) applied
// on the *global source* column so global_load_lds stays linear; reads apply
// the same XOR -> conflict-free ds_read_b128.
template<int OUT_F32>
__global__ __launch_bounds__(256)
void gemm_bt(const u16* __restrict__ A, const u16* __restrict__ Bm,
             void* __restrict__ Cp, int N, int K)
{
  __shared__ alignas(16) u16 lA[128 * 64];
  __shared__ alignas(16) u16 lB[128 * 64];
  const int tid = threadIdx.x;
  const int w = tid >> 6, l = tid & 63;
  const int lg = l >> 4, lc = l & 15;
  const int wm = w >> 1, wn = w & 1;
  const int m0 = blockIdx.y * 128, n0 = blockIdx.x * 128;
  const int srow = l >> 3, sc = l & 7;
  const size_t ldb = (size_t)K * 2;   // row bytes
  f32x4 acc[4][4] = {};
  const int kiters = K >> 6;
  for (int kt = 0; kt < kiters; ++kt){
    __syncthreads();
#pragma unroll
    for (int i = 0; i < 4; ++i){
      const int row = (i * 4 + w) * 8 + srow;
      const int gc = ((sc ^ (row & 7)) << 4);
      gload_lds16((const char*)A + (size_t)(m0 + row) * ldb + (size_t)kt * 128 + gc,
                  (char*)lA + row * 128 + sc * 16);
    }
#pragma unroll
    for (int i = 0; i < 4; ++i){
      const int row = (i * 4 + w) * 8 + srow;
      const int gc = ((sc ^ (row & 7)) << 4);
      gload_lds16((const char*)Bm + (size_t)(n0 + row) * ldb + (size_t)kt * 128 + gc,
                  (char*)lB + row * 128 + sc * 16);
    }
    __syncthreads();
#pragma unroll
    for (int kk = 0; kk < 2; ++kk){
      short8 af[4], bfr[4];
#pragma unroll
      for (int mi = 0; mi < 4; ++mi){
        const int row = wm * 64 + mi * 16 + lc;
        const int cc = (kk * 4 + lg) ^ (row & 7);
        af[mi] = *(const short8*)((const char*)lA + row * 128 + cc * 16);
      }
#pragma unroll
      for (int ni = 0; ni < 4; ++ni){
        const int row = wn * 64 + ni * 16 + lc;
        const int cc = (kk * 4 + lg) ^ (row & 7);
        bfr[ni] = *(const short8*)((const char*)lB + row * 128 + cc * 16);
      }
#pragma unroll
      for (int mi = 0; mi < 4; ++mi)
#pragma unroll
        for (int ni = 0; ni < 4; ++ni)
          acc[mi][ni] = __builtin_amdgcn_mfma_f32_16x16x32_bf16(af[mi], bfr[ni], acc[mi][ni], 0, 0, 0);
    }
  }
  // epilogue: C/D layout col = lane&15, row = (lane>>4)*4 + reg  [m89-verified]
  const int r0 = m0 + wm * 64 + lg * 4;
  const int c0 = n0 + wn * 64 + lc;
#pragma unroll
  for (int mi = 0; mi < 4; ++mi)
#pragma unroll
    for (int ni = 0; ni < 4; ++ni)
#pragma unroll
      for (int j = 0; j < 4; ++j){
        const size_t idx = (size_t)(r0 + mi * 16 + j) * (size_t)N + (size_t)(c0 + ni * 16);
        if (OUT_F32) ((float*)Cp)[idx] = acc[mi][ni][j];
        else         ((u16*)Cp)[idx]  = f2b(acc[mi][ni][j]);
      }
}

// ---------------- RoPE + scales; qkv[b][s][48][64] -> Q[b][h][s][64], K[b][kh][s][64] ----------------
__global__ __launch_bounds__(256)
void rope_kernel(const u16* __restrict__ qkv, const float* __restrict__ cosT,
                 const float* __restrict__ sinT, const float* __restrict__ phs,
                 u16* __restrict__ Qo, u16* __restrict__ Ko)
{
  int id = blockIdx.x * 256 + threadIdx.x;      // B*40*S*4 = 655360
  int b = (id >= 327680) ? 1 : 0;
  int rem = id - b * 327680;
  int head = rem >> 13;                         // 0..39
  int s = (rem >> 2) & 2047;
  int d0 = (rem & 3) << 4;                      // 0,16,32,48
  const u16* src = qkv + (((size_t)(b * S_LEN + s) * 48 + head) << 6);
  uint4 xa = *(const uint4*)(src + d0);
  uint4 xb = *(const uint4*)(src + d0 + 8);
  int d0p = (d0 + 32) & 63;
  uint4 pa = *(const uint4*)(src + d0p);
  uint4 pb = *(const uint4*)(src + d0p + 8);
  const float* cp = cosT + s * 64 + d0;
  const float* sp = sinT + s * 64 + d0;
  const float sgn = (d0 < 32) ? -1.f : 1.f;
  const float scale = 1.2f * (head < NQH ? phs[b * NQH + head] : 1.f);
  uint32_t xs[4] = {xa.x, xa.y, xa.z, xa.w};
  uint32_t xs2[4] = {xb.x, xb.y, xb.z, xb.w};
  uint32_t ps[4] = {pa.x, pa.y, pa.z, pa.w};
  uint32_t ps2[4] = {pb.x, pb.y, pb.z, pb.w};
  uint32_t ow[8];
#pragma unroll
  for (int k = 0; k < 4; ++k){
    float v0 = b2f((u16)(xs[k] & 0xffff)) * cp[2*k]   + sgn * b2f((u16)(ps[k] & 0xffff)) * sp[2*k];
    float v1 = b2f((u16)(xs[k] >> 16))    * cp[2*k+1] + sgn * b2f((u16)(ps[k] >> 16))    * sp[2*k+1];
    ow[k] = (uint32_t)f2b(v0 * scale) | ((uint32_t)f2b(v1 * scale) << 16);
  }
#pragma unroll
  for (int k = 0; k < 4; ++k){
    float v0 = b2f((u16)(xs2[k] & 0xffff)) * cp[8+2*k]   + sgn * b2f((u16)(ps2[k] & 0xffff)) * sp[8+2*k];
    float v1 = b2f((u16)(xs2[k] >> 16))    * cp[8+2*k+1] + sgn * b2f((u16)(ps2[k] >> 16))    * sp[8+2*k+1];
    ow[4+k] = (uint32_t)f2b(v0 * scale) | ((uint32_t)f2b(v1 * scale) << 16);
  }
  u16* dst;
  if (head < NQH) dst = Qo + (((size_t)(b * NQH + head) * S_LEN + s) << 6) + d0;
  else            dst = Ko + (((size_t)(b * NKH + head - NQH) * S_LEN + s) << 6) + d0;
  uint4 o0 = {ow[0], ow[1], ow[2], ow[3]};
  uint4 o1 = {ow[4], ow[5], ow[6], ow[7]};
  *(uint4*)dst = o0;
  *(uint4*)(dst + 8) = o1;
}

// ---------------- V transpose: qkv v-heads -> VT[b][kh][d][s] ----------------
__global__ __launch_bounds__(256)
void vtrans(const u16* __restrict__ qkv, u16* __restrict__ VT)
{
  int bid = blockIdx.x;                 // (b*8+kh)*32 + st
  int st = bid & 31, kh = (bid >> 5) & 7, b = bid >> 8;
  __shared__ alignas(16) u16 t[64][72];
  int tid = threadIdx.x;
  int r = tid >> 2, c4 = tid & 3;
  const u16* src = qkv + (((size_t)(b * S_LEN + st * 64 + r) * 48 + 40 + kh) << 6) + c4 * 16;
  *(uint4*)&t[r][c4 * 16]     = *(const uint4*)src;
  *(uint4*)&t[r][c4 * 16 + 8] = *(const uint4*)(src + 8);
  __syncthreads();
  u16 o[16];
#pragma unroll
  for (int i = 0; i < 16; ++i) o[i] = t[c4 * 16 + i][r];   // r = d row now
  u16* dst = VT + ((size_t)(b * NKH + kh) * 64 + r) * S_LEN + st * 64 + c4 * 16;
  uint4 o0 = { (uint32_t)o[0] | ((uint32_t)o[1] << 16),  (uint32_t)o[2] | ((uint32_t)o[3] << 16),
               (uint32_t)o[4] | ((uint32_t)o[5] << 16),  (uint32_t)o[6] | ((uint32_t)o[7] << 16) };
  uint4 o1 = { (uint32_t)o[8] | ((uint32_t)o[9] << 16),  (uint32_t)o[10] | ((uint32_t)o[11] << 16),
               (uint32_t)o[12] | ((uint32_t)o[13] << 16),(uint32_t)o[14] | ((uint32_t)o[15] << 16) };
  *(uint4*)dst = o0;
  *(uint4*)(dst + 8) = o1;
}

// ---------------- causal GQA flash attention ----------------
// block: (b, kh, g, q-tile of 128). 4 waves x 32 q-rows. BKV=64.
__global__ __launch_bounds__(256)
void attn_kernel(const u16* __restrict__ Q, const u16* __restrict__ Kr,
                 const u16* __restrict__ VT, u16* __restrict__ Ao)
{
  int bid = blockIdx.x;
  int qb = 15 - (bid & 15);            // big tiles dispatched first
  int g  = (bid >> 4) & 3;
  int kh = (bid >> 6) & 7;
  int b  = bid >> 9;
  int h = kh * 4 + g;
  int q0 = qb * 128;

  __shared__ alignas(16) u16 lK[64 * 64];       // [j][d], swizzled
  __shared__ alignas(16) u16 lV[64 * 64];       // [d][j], swizzled
  __shared__ alignas(16) u16 lP[4][32][72];     // per-wave P [q][j], pad 8

  const int tid = threadIdx.x;
  const int w = tid >> 6, l = tid & 63;
  const int lg = l >> 4, lc = l & 15;
  const int srow = l >> 3, sc = l & 7;

  // Q fragments (rows w*32 + mi*16 + lc, k = kk*32 + lg*8)
  short8 qf[2][2];
  {
    const u16* qbase = Q + ((size_t)(b * NQH + h) * S_LEN + q0 + w * 32) * 64;
#pragma unroll
    for (int mi = 0; mi < 2; ++mi)
#pragma unroll
      for (int kk = 0; kk < 2; ++kk)
        qf[mi][kk] = *(const short8*)(qbase + (size_t)(mi * 16 + lc) * 64 + kk * 32 + lg * 8);
  }

  const u16* Kb = Kr + (size_t)(b * NKH + kh) * S_LEN * 64;
  const u16* Vb = VT + (size_t)(b * NKH + kh) * 64 * S_LEN;

  f32x4 o[2][4] = {};
  f32x4 mrow[2], lsum[2];
#pragma unroll
  for (int mi = 0; mi < 2; ++mi)
#pragma unroll
    for (int j = 0; j < 4; ++j){ mrow[mi][j] = -3.0e38f; lsum[mi][j] = 0.f; }

  const int ntiles = qb * 2 + 2;
  for (int t = 0; t < ntiles; ++t){
    __syncthreads();
    // stage K tile (rows j), V^T tile (rows d); swizzled global source cols
#pragma unroll
    for (int i = 0; i < 2; ++i){
      const int row = (i * 4 + w) * 8 + srow;
      const int gc = ((sc ^ (row & 7)) << 4);
      gload_lds16((const char*)(Kb + (size_t)(t * 64 + row) * 64) + gc,
                  (char*)lK + row * 128 + sc * 16);
    }
#pragma unroll
    for (int i = 0; i < 2; ++i){
      const int row = (i * 4 + w) * 8 + srow;
      const int gc = ((sc ^ (row & 7)) << 4);
      gload_lds16((const char*)(Vb + (size_t)row * S_LEN + t * 64) + gc,
                  (char*)lV + row * 128 + sc * 16);
    }
    __syncthreads();

    // S = Q K^T
    f32x4 sv[2][4] = {};
#pragma unroll
    for (int kk = 0; kk < 2; ++kk){
      short8 kf[4];
#pragma unroll
      for (int nj = 0; nj < 4; ++nj){
        const int row = nj * 16 + lc;
        const int cc = (kk * 4 + lg) ^ (row & 7);
        kf[nj] = *(const short8*)((const char*)lK + row * 128 + cc * 16);
      }
#pragma unroll
      for (int mi = 0; mi < 2; ++mi)
#pragma unroll
        for (int nj = 0; nj < 4; ++nj)
          sv[mi][nj] = __builtin_amdgcn_mfma_f32_16x16x32_bf16(qf[mi][kk], kf[nj], sv[mi][nj], 0, 0, 0);
    }

    // mask + online softmax
#pragma unroll
    for (int mi = 0; mi < 2; ++mi){
      const int rbase = q0 + w * 32 + mi * 16 + lg * 4;
#pragma unroll
      for (int nj = 0; nj < 4; ++nj){
        const int col = t * 64 + nj * 16 + lc;
#pragma unroll
        for (int j = 0; j < 4; ++j){
          float v = sv[mi][nj][j] * 0.125f;
          sv[mi][nj][j] = (col <= rbase + j) ? v : -3.0e38f;
        }
      }
      f32x4 pmax;
#pragma unroll
      for (int j = 0; j < 4; ++j)
        pmax[j] = fmaxf(fmaxf(sv[mi][0][j], sv[mi][1][j]), fmaxf(sv[mi][2][j], sv[mi][3][j]));
#pragma unroll
      for (int off = 1; off < 16; off <<= 1)
#pragma unroll
        for (int j = 0; j < 4; ++j)
          pmax[j] = fmaxf(pmax[j], __shfl_xor(pmax[j], off));
      f32x4 mnew, sf;
#pragma unroll
      for (int j = 0; j < 4; ++j){
        mnew[j] = fmaxf(mrow[mi][j], pmax[j]);
        sf[j] = __expf(mrow[mi][j] - mnew[j]);
        mrow[mi][j] = mnew[j];
      }
      f32x4 psum = {0.f, 0.f, 0.f, 0.f};
#pragma unroll
      for (int nj = 0; nj < 4; ++nj)
#pragma unroll
        for (int j = 0; j < 4; ++j){
          float p = __expf(sv[mi][nj][j] - mnew[j]);
          sv[mi][nj][j] = p;
          psum[j] += p;
        }
#pragma unroll
      for (int off = 1; off < 16; off <<= 1)
#pragma unroll
        for (int j = 0; j < 4; ++j)
          psum[j] += __shfl_xor(psum[j], off);
#pragma unroll
      for (int j = 0; j < 4; ++j)
        lsum[mi][j] = lsum[mi][j] * sf[j] + psum[j];
#pragma unroll
      for (int dn = 0; dn < 4; ++dn)
#pragma unroll
        for (int j = 0; j < 4; ++j)
          o[mi][dn][j] *= sf[j];
      // P -> LDS (bf16), C-layout rows (lg*4+j), cols (nj*16+lc)
#pragma unroll
      for (int nj = 0; nj < 4; ++nj)
#pragma unroll
        for (int j = 0; j < 4; ++j)
          lP[w][mi * 16 + lg * 4 + j][nj * 16 + lc] = f2b(sv[mi][nj][j]);
    }

    // O += P V  (A = P from LDS, B = V^T tile)
#pragma unroll
    for (int kk2 = 0; kk2 < 2; ++kk2){
      short8 pa[2], vf[4];
#pragma unroll
      for (int mi = 0; mi < 2; ++mi)
        pa[mi] = *(const short8*)&lP[w][mi * 16 + lc][kk2 * 32 + lg * 8];
#pragma unroll
      for (int dn = 0; dn < 4; ++dn){
        const int row = dn * 16 + lc;
        const int cc = (kk2 * 4 + lg) ^ (row & 7);
        vf[dn] = *(const short8*)((const char*)lV + row * 128 + cc * 16);
      }
#pragma unroll
      for (int mi = 0; mi < 2; ++mi)
#pragma unroll
        for (int dn = 0; dn < 4; ++dn)
          o[mi][dn] = __builtin_amdgcn_mfma_f32_16x16x32_bf16(pa[mi], vf[dn], o[mi][dn], 0, 0, 0);
    }
  }

  // epilogue: normalize + write attn_out[b][s][h*64+d] (bf16)
#pragma unroll
  for (int mi = 0; mi < 2; ++mi){
    f32x4 inv;
#pragma unroll
    for (int j = 0; j < 4; ++j) inv[j] = 1.f / lsum[mi][j];
#pragma unroll
    for (int dn = 0; dn < 4; ++dn)
#pragma unroll
      for (int j = 0; j < 4; ++j){
        const int row = q0 + w * 32 + mi * 16 + lg * 4 + j;
        const int col = h * 64 + dn * 16 + lc;
        Ao[(size_t)(b * S_LEN + row) * 2048 + col] = f2b(o[mi][dn][j] * inv[j]);
      }
  }
}

// ---------------- launcher ----------------
extern "C" void kernel_launch(void* const* d_in, const int* in_sizes, int n_in,
                              void* d_out, int out_size, void* d_ws, size_t ws_size,
                              hipStream_t stream)
{
  const float* cosT = (const float*)d_in[0];
  const float* sinT = (const float*)d_in[1];
  const float* hs   = (const float*)d_in[2];
  const float* phs  = (const float*)d_in[3];
  const float* Wqkv = (const float*)d_in[4];
  const float* Wo   = (const float*)d_in[5];
  float* out = (float*)d_out;
  char* ws = (char*)d_ws;

  u16* hsB   = (u16*)(ws);               // 16,777,216 B (aliased as attn_out later)
  u16* WqkvB = (u16*)(ws + 16777216);    // 12,582,912 B
  u16* WoB   = (u16*)(ws + 29360128);    //  8,388,608 B
  u16* qkvB  = (u16*)(ws + 37748736);    // 25,165,824 B
  u16* Qb    = (u16*)(ws + 62914560);    // 16,777,216 B
  u16* Kb    = (u16*)(ws + 79691776);    //  4,194,304 B
  u16* VTb   = (u16*)(ws + 83886080);    //  4,194,304 B  (total 88,080,384 B)
  u16* Ao    = hsB;                      // hsB dead after GEMM1

  cvt_f32_bf16<<<8192, 256, 0, stream>>>(hs,   hsB,   2097152);
  cvt_f32_bf16<<<6144, 256, 0, stream>>>(Wqkv, WqkvB, 1572864);
  cvt_f32_bf16<<<4096, 256, 0, stream>>>(Wo,   WoB,   1048576);
  gemm_bt<0><<<dim3(24, 32), 256, 0, stream>>>(hsB, WqkvB, (void*)qkvB, 3072, 2048);
  rope_kernel<<<2560, 256, 0, stream>>>(qkvB, cosT, sinT, phs, Qb, Kb);
  vtrans<<<512, 256, 0, stream>>>(qkvB, VTb);
  attn_kernel<<<1024, 256, 0, stream>>>(Qb, Kb, VTb, Ao);
  gemm_bt<1><<<dim3(16, 32), 256, 0, stream>>>(Ao, WoB, (void*)out, 2048, 2048);
}